// Round 14
// baseline (576.173 us; speedup 1.0000x reference)
//
#include <hip/hip_runtime.h>

// ---------------------------------------------------------------------------
// GIN encoder, fp16 path + MFMA. ROUND-14 A/B: layers 0,2 use XCD-PINNED
// COLUMN-SLICE aggregation (slice = blockIdx&7 -> all blocks of slice s run
// on XCD s; per-XCD gather working set = 50k x 32B = 1.6MB, L2-resident by
// construction; aggbuf written nontemporal to keep L2 clean) followed by a
// separate MLP kernel. Layers 1,3 run the round-13 fused kernel (control).
// Per-dispatch dur_us/FETCH from rocprof = the A/B readout.
// CSR build (round 13, validated): prep_fused + cscan + sortA + sortB.
// ---------------------------------------------------------------------------

typedef __attribute__((ext_vector_type(8))) _Float16 f16x8;
typedef __attribute__((ext_vector_type(4))) float f32x4;
typedef __attribute__((ext_vector_type(4))) unsigned int u32x4;

static __device__ __forceinline__ float h2f(unsigned short u) {
  return (float)__builtin_bit_cast(_Float16, u);
}
static __device__ __forceinline__ unsigned short f2h(float f) {
  return __builtin_bit_cast(unsigned short, (_Float16)f);
}
static __device__ __forceinline__ float lo16(unsigned int v) { return h2f((unsigned short)(v & 0xffffu)); }
static __device__ __forceinline__ float hi16(unsigned int v) { return h2f((unsigned short)(v >> 16)); }

#define HB 392

// ---- fused prep: x->fp16, W->WT, affine init, coarse dst-hist partials ----
__global__ __launch_bounds__(256) void prep_fused_kernel(
    const float* __restrict__ x, unsigned int* __restrict__ h,
    const float* __restrict__ W1, const float* __restrict__ W2,
    unsigned short* __restrict__ WT, const int* __restrict__ dst,
    int* __restrict__ partial, float* __restrict__ scale, float* __restrict__ shift,
    int M, int E, int Ltot) {
  __shared__ int hcnt[128];
  int t = threadIdx.x;
  int tid = blockIdx.x * 256 + t;
  int stride = gridDim.x * 256;
  bool doHist = (blockIdx.x < HB);
  if (doHist) {
    if (t < 128) hcnt[t] = 0;
    __syncthreads();
    for (int e = blockIdx.x * 256 + t; e < E; e += HB * 256)
      atomicAdd(&hcnt[dst[e] >> 9], 1);
  }
  const float2* x2 = (const float2*)x;
  int total = M * 64;
  for (int i = tid; i < total; i += stride) {
    float2 v = x2[i];
    h[i] = (unsigned int)f2h(v.x) | ((unsigned int)f2h(v.y) << 16);
  }
  int wtotal = Ltot * 2 * 16384;
  for (int idx = tid; idx < wtotal; idx += stride) {
    int m = idx >> 14;
    int rem = idx & 16383;
    int n = rem >> 7, k = rem & 127;
    const float* W = ((m & 1) == 0) ? (W1 + (size_t)(m >> 1) * 16384)
                                    : (W2 + (size_t)(m >> 1) * 16384);
    WT[idx] = f2h(W[k * 128 + n]);
  }
  if (tid < 128) { scale[tid] = 1.f; shift[tid] = 0.f; }
  if (doHist) {
    __syncthreads();
    if (t < 128) partial[blockIdx.x * 128 + t] = hcnt[t];
  }
}

__global__ __launch_bounds__(128) void cscan_kernel(const int* __restrict__ partial,
                                                    int* __restrict__ ccursor,
                                                    int* __restrict__ cbase, int E) {
  __shared__ int buf[2][128];
  int t = threadIdx.x;
  int s = 0;
  for (int k = 0; k < HB; ++k) s += partial[k * 128 + t];
  buf[0][t] = s;
  __syncthreads();
  int cur = 0;
  for (int off = 1; off < 128; off <<= 1) {
    buf[cur ^ 1][t] = buf[cur][t] + ((t >= off) ? buf[cur][t - off] : 0);
    __syncthreads();
    cur ^= 1;
  }
  int excl = buf[cur][t] - s;
  ccursor[t] = excl;
  cbase[t] = excl;
  if (t == 127) cbase[128] = E;
}

#define EPB 4096
__global__ __launch_bounds__(256) void sortA_kernel(const int* __restrict__ src,
                                                    const int* __restrict__ dst,
                                                    int* __restrict__ ccursor,
                                                    unsigned int* __restrict__ tmp, int E) {
  __shared__ int cnt[128], pref[128], gbase[128];
  __shared__ int scanbuf[2][128];
  __shared__ unsigned int vals[EPB];
  int t = threadIdx.x;
  int base = blockIdx.x * EPB;
  int nloc = min(EPB, E - base);
  if (t < 128) cnt[t] = 0;
  __syncthreads();

  unsigned int vj[16];
  int rj[16];
#pragma unroll
  for (int j = 0; j < 16; ++j) {
    int e = base + j * 256 + t;
    vj[j] = 0u;
    rj[j] = -1;
    if (e < base + nloc) {
      int s = src[e], d = dst[e];
      unsigned int v = ((unsigned int)d << 16) | (unsigned int)s;
      vj[j] = v;
      rj[j] = atomicAdd(&cnt[v >> 25], 1);
    }
  }
  __syncthreads();
  if (t < 128) scanbuf[0][t] = cnt[t];
  __syncthreads();
  int cur = 0;
  for (int off = 1; off < 128; off <<= 1) {
    if (t < 128) scanbuf[cur ^ 1][t] = scanbuf[cur][t] + ((t >= off) ? scanbuf[cur][t - off] : 0);
    __syncthreads();
    cur ^= 1;
  }
  if (t < 128) pref[t] = scanbuf[cur][t] - cnt[t];
  __syncthreads();
  if (t < 128 && cnt[t] > 0) gbase[t] = atomicAdd(&ccursor[t], cnt[t]);
  __syncthreads();
#pragma unroll
  for (int j = 0; j < 16; ++j) {
    if (rj[j] >= 0) vals[pref[vj[j] >> 25] + rj[j]] = vj[j];
  }
  __syncthreads();
  for (int j = t; j < nloc; j += 256) {
    unsigned int v = vals[j];
    int b = v >> 25;
    tmp[gbase[b] + (j - pref[b])] = v;
  }
}

__global__ __launch_bounds__(512) void sortB_kernel(const unsigned int* __restrict__ tmp,
                                                    const int* __restrict__ cbase,
                                                    int* __restrict__ offsets,
                                                    unsigned short* __restrict__ srcs,
                                                    int M, int E) {
  __shared__ int lcnt[512];
  __shared__ int sbuf[2][512];
  int b = blockIdx.x;
  int t = threadIdx.x;
  int e0 = cbase[b], e1 = cbase[b + 1];
  int r0 = b << 9;
  lcnt[t] = 0;
  __syncthreads();
  for (int e = e0 + t; e < e1; e += 512) atomicAdd(&lcnt[(tmp[e] >> 16) & 511], 1);
  __syncthreads();
  sbuf[0][t] = lcnt[t];
  __syncthreads();
  int cur = 0;
  for (int off = 1; off < 512; off <<= 1) {
    sbuf[cur ^ 1][t] = sbuf[cur][t] + ((t >= off) ? sbuf[cur][t - off] : 0);
    __syncthreads();
    cur ^= 1;
  }
  int excl = sbuf[cur][t] - lcnt[t];
  int r = r0 + t;
  if (r < M) offsets[r] = e0 + excl;
  if (r == M - 1) offsets[M] = E;
  __syncthreads();
  lcnt[t] = e0 + excl;
  __syncthreads();
  for (int e = e0 + t; e < e1; e += 512) {
    unsigned int v = tmp[e];
    int p = atomicAdd(&lcnt[(v >> 16) & 511], 1);
    srcs[p] = (unsigned short)(v & 0xffffu);
  }
}

// ---- NEW: XCD-pinned column-slice aggregation ----
// slice = blockIdx&7 (hardware dispatches blockIdx round-robin over the 8
// XCDs, so all slice-s blocks share XCD s and its L2 holds the 1.6MB slice).
// Wave = 8 edges x 8 uint-cols; shfl_xor(8/16/32) reduces edge slots.
__global__ __launch_bounds__(256) void agg_kernel(
    const unsigned int* __restrict__ Hin, const int* __restrict__ offsets,
    const unsigned short* __restrict__ srcs, const float* __restrict__ scale,
    const float* __restrict__ shift, unsigned int* __restrict__ agg, int M) {
  int slice = blockIdx.x & 7;
  int tile = blockIdx.x >> 3;
  int t = threadIdx.x;
  int wave = t >> 6, lane = t & 63;
  int es = lane >> 3;   // edge slot 0..7
  int c = lane & 7;     // uint col within slice
  int colu = slice * 8 + c;
  float sc0 = scale[colu * 2], sc1 = scale[colu * 2 + 1];
  float sh0 = shift[colu * 2], sh1 = shift[colu * 2 + 1];
  for (int i = 0; i < 8; ++i) {
    int r = tile * 32 + wave * 8 + i;
    if (r >= M) break;
    int e0 = offsets[r], e1 = offsets[r + 1];
    float ax = 0.f, ay = 0.f;
    for (int base = e0; base < e1; base += 8) {
      int ee = base + es;
      unsigned int v = 0u;
      if (ee < e1) {
        int s = srcs[ee];
        v = Hin[(size_t)s * 64 + colu];
      }
      ax += lo16(v);
      ay += hi16(v);
    }
    ax += __shfl_xor(ax, 8);  ay += __shfl_xor(ay, 8);
    ax += __shfl_xor(ax, 16); ay += __shfl_xor(ay, 16);
    ax += __shfl_xor(ax, 32); ay += __shfl_xor(ay, 32);
    if (es == 0) {
      unsigned int sv = Hin[(size_t)r * 64 + colu];
      ax += lo16(sv);
      ay += hi16(sv);
      float d1 = (float)(e1 - e0 + 1);
      unsigned int o = (unsigned int)f2h(ax * sc0 + d1 * sh0) |
                       ((unsigned int)f2h(ay * sc1 + d1 * sh1) << 16);
      __builtin_nontemporal_store(o, &agg[(size_t)r * 64 + colu]);
    }
  }
}

// ---- NEW: MLP-only kernel (agg already BN'd): LDS <- agg, GEMM1, GEMM2 ----
__global__ __launch_bounds__(512, 8) void mlp_kernel(
    const unsigned int* __restrict__ agg,  // M x 64 uints
    const unsigned short* __restrict__ WT1, const float* __restrict__ b1,
    const unsigned short* __restrict__ WT2, const float* __restrict__ b2,
    unsigned short* __restrict__ Hout, float* __restrict__ pstat, int M) {
  __shared__ unsigned short sT[32 * 128];
  __shared__ float s_sum[128], s_sq[128];
  int t = threadIdx.x;
  if (t < 128) { s_sum[t] = 0.f; s_sq[t] = 0.f; }
  int wave = t >> 6, lane = t & 63;
  int row0 = blockIdx.x * 32;
  char* sTb = (char*)sT;
  {
    int rl_ = t >> 4;   // 0..31
    int u4 = t & 15;    // uint4 col 0..15
    int r = row0 + rl_;
    u32x4 v = (u32x4){0u, 0u, 0u, 0u};
    if (r < M) v = *(const u32x4*)(agg + (size_t)r * 64 + u4 * 4);
    *(u32x4*)(sTb + rl_ * 256 + ((u4 * 16) ^ ((rl_ & 7) << 4))) = v;
  }
  __syncthreads();

  int wr = wave & 1, wc = wave >> 1;
  int lrow = lane & 15, hi = lane >> 4;
  int lk = hi * 8;
  int rl = wr * 16 + lrow;

  f16x8 af[4];
#pragma unroll
  for (int ks = 0; ks < 4; ++ks)
    af[ks] = *(const f16x8*)(sTb + rl * 256 + ((ks * 64 + hi * 16) ^ ((rl & 7) << 4)));
  f32x4 acc[2];
#pragma unroll
  for (int n = 0; n < 2; ++n) acc[n] = (f32x4){0.f, 0.f, 0.f, 0.f};
#pragma unroll
  for (int ks = 0; ks < 4; ++ks) {
    f16x8 bf[2];
#pragma unroll
    for (int n = 0; n < 2; ++n)
      bf[n] = *(const f16x8*)(WT1 + (size_t)(wc * 32 + n * 16 + lrow) * 128 + ks * 32 + lk);
#pragma unroll
    for (int n = 0; n < 2; ++n)
      acc[n] = __builtin_amdgcn_mfma_f32_16x16x32_f16(af[ks], bf[n], acc[n], 0, 0, 0);
  }
  __syncthreads();

#pragma unroll
  for (int n = 0; n < 2; ++n) {
    int col = wc * 32 + n * 16 + lrow;
    float bia = b1[col];
#pragma unroll
    for (int r = 0; r < 4; ++r) {
      int rlw = wr * 16 + hi * 4 + r;
      float v = fmaxf(acc[n][r] + bia, 0.f);
      *(unsigned short*)(sTb + rlw * 256 + ((col * 2) ^ ((rlw & 7) << 4))) = f2h(v);
    }
  }
  __syncthreads();

#pragma unroll
  for (int ks = 0; ks < 4; ++ks)
    af[ks] = *(const f16x8*)(sTb + rl * 256 + ((ks * 64 + hi * 16) ^ ((rl & 7) << 4)));
#pragma unroll
  for (int n = 0; n < 2; ++n) acc[n] = (f32x4){0.f, 0.f, 0.f, 0.f};
#pragma unroll
  for (int ks = 0; ks < 4; ++ks) {
    f16x8 bf[2];
#pragma unroll
    for (int n = 0; n < 2; ++n)
      bf[n] = *(const f16x8*)(WT2 + (size_t)(wc * 32 + n * 16 + lrow) * 128 + ks * 32 + lk);
#pragma unroll
    for (int n = 0; n < 2; ++n)
      acc[n] = __builtin_amdgcn_mfma_f32_16x16x32_f16(af[ks], bf[n], acc[n], 0, 0, 0);
  }

  int rbase = row0 + wr * 16 + hi * 4;
#pragma unroll
  for (int n = 0; n < 2; ++n) {
    int col = wc * 32 + n * 16 + lrow;
    float bia = b2[col];
    float cs = 0.f, cq = 0.f;
#pragma unroll
    for (int r = 0; r < 4; ++r) {
      int rr = rbase + r;
      float v = fmaxf(acc[n][r] + bia, 0.f);
      if (rr < M) {
        Hout[(size_t)rr * 128 + col] = f2h(v);
        cs += v;
        cq += v * v;
      }
    }
    cs += __shfl_xor(cs, 16); cs += __shfl_xor(cs, 32);
    cq += __shfl_xor(cq, 16); cq += __shfl_xor(cq, 32);
    if (hi == 0) {
      atomicAdd(&s_sum[col], cs);
      atomicAdd(&s_sq[col], cq);
    }
  }
  __syncthreads();
  if (t < 128) {
    float* p = pstat + (size_t)blockIdx.x * 256;
    p[t] = s_sum[t];
    p[t + 128] = s_sq[t];
  }
}

// ---- fused layer (round-13 control, layers 1,3) ----
__global__ __launch_bounds__(512, 8) void layer_kernel(
    const unsigned int* __restrict__ Hin, const int* __restrict__ offsets,
    const unsigned short* __restrict__ srcs,
    const float* __restrict__ scale, const float* __restrict__ shift,
    const unsigned short* __restrict__ WT1, const float* __restrict__ b1,
    const unsigned short* __restrict__ WT2, const float* __restrict__ b2,
    unsigned short* __restrict__ Hout, float* __restrict__ pstat, int M) {
  __shared__ unsigned short sT[32 * 128];
  __shared__ float s_sum[128], s_sq[128];
  int t = threadIdx.x;
  if (t < 128) { s_sum[t] = 0.f; s_sq[t] = 0.f; }
  int wave = t >> 6, lane = t & 63;
  int row0 = blockIdx.x * 32;
  char* sTb = (char*)sT;
  float sc0 = scale[2 * lane], sc1 = scale[2 * lane + 1];
  float sh0 = shift[2 * lane], sh1 = shift[2 * lane + 1];

  for (int i = 0; i < 4; i += 2) {
    int rA = row0 + wave * 4 + i;
    int rB = rA + 1;
    float axA = 0.f, ayA = 0.f, axB = 0.f, ayB = 0.f;
    int eA = 0, eA1 = 0, eB = 0, eB1 = 0;
    if (rA < M) {
      eA = offsets[rA]; eA1 = offsets[rA + 1];
      unsigned int s = Hin[(size_t)rA * 64 + lane];
      axA = lo16(s); ayA = hi16(s);
    }
    if (rB < M) {
      eB = offsets[rB]; eB1 = offsets[rB + 1];
      unsigned int s = Hin[(size_t)rB * 64 + lane];
      axB = lo16(s); ayB = hi16(s);
    }
    int dA = eA1 - eA, dB = eB1 - eB;
    while (eA + 4 <= eA1 && eB + 4 <= eB1) {
      int a0 = srcs[eA], a1 = srcs[eA + 1], a2 = srcs[eA + 2], a3 = srcs[eA + 3];
      int c0 = srcs[eB], c1 = srcs[eB + 1], c2 = srcs[eB + 2], c3 = srcs[eB + 3];
      unsigned int vA0 = Hin[(size_t)a0 * 64 + lane];
      unsigned int vA1 = Hin[(size_t)a1 * 64 + lane];
      unsigned int vA2 = Hin[(size_t)a2 * 64 + lane];
      unsigned int vA3 = Hin[(size_t)a3 * 64 + lane];
      unsigned int vB0 = Hin[(size_t)c0 * 64 + lane];
      unsigned int vB1 = Hin[(size_t)c1 * 64 + lane];
      unsigned int vB2 = Hin[(size_t)c2 * 64 + lane];
      unsigned int vB3 = Hin[(size_t)c3 * 64 + lane];
      axA += lo16(vA0) + lo16(vA1) + lo16(vA2) + lo16(vA3);
      ayA += hi16(vA0) + hi16(vA1) + hi16(vA2) + hi16(vA3);
      axB += lo16(vB0) + lo16(vB1) + lo16(vB2) + lo16(vB3);
      ayB += hi16(vB0) + hi16(vB1) + hi16(vB2) + hi16(vB3);
      eA += 4; eB += 4;
    }
    while (eA + 4 <= eA1) {
      int a0 = srcs[eA], a1 = srcs[eA + 1], a2 = srcs[eA + 2], a3 = srcs[eA + 3];
      unsigned int v0 = Hin[(size_t)a0 * 64 + lane];
      unsigned int v1 = Hin[(size_t)a1 * 64 + lane];
      unsigned int v2 = Hin[(size_t)a2 * 64 + lane];
      unsigned int v3 = Hin[(size_t)a3 * 64 + lane];
      axA += lo16(v0) + lo16(v1) + lo16(v2) + lo16(v3);
      ayA += hi16(v0) + hi16(v1) + hi16(v2) + hi16(v3);
      eA += 4;
    }
    while (eB + 4 <= eB1) {
      int c0 = srcs[eB], c1 = srcs[eB + 1], c2 = srcs[eB + 2], c3 = srcs[eB + 3];
      unsigned int v0 = Hin[(size_t)c0 * 64 + lane];
      unsigned int v1 = Hin[(size_t)c1 * 64 + lane];
      unsigned int v2 = Hin[(size_t)c2 * 64 + lane];
      unsigned int v3 = Hin[(size_t)c3 * 64 + lane];
      axB += lo16(v0) + lo16(v1) + lo16(v2) + lo16(v3);
      ayB += hi16(v0) + hi16(v1) + hi16(v2) + hi16(v3);
      eB += 4;
    }
    for (; eA < eA1; ++eA) {
      unsigned int v = Hin[(size_t)srcs[eA] * 64 + lane];
      axA += lo16(v); ayA += hi16(v);
    }
    for (; eB < eB1; ++eB) {
      unsigned int v = Hin[(size_t)srcs[eB] * 64 + lane];
      axB += lo16(v); ayB += hi16(v);
    }
    int rlA = wave * 4 + i, rlB = rlA + 1;
    float dA1 = (float)(dA + 1), dB1 = (float)(dB + 1);
    unsigned int oA = (unsigned int)f2h(axA * sc0 + dA1 * sh0) |
                      ((unsigned int)f2h(ayA * sc1 + dA1 * sh1) << 16);
    unsigned int oB = (unsigned int)f2h(axB * sc0 + dB1 * sh0) |
                      ((unsigned int)f2h(ayB * sc1 + dB1 * sh1) << 16);
    *(unsigned int*)(sTb + rlA * 256 + ((lane * 4) ^ ((rlA & 7) << 4))) = (rA < M) ? oA : 0u;
    *(unsigned int*)(sTb + rlB * 256 + ((lane * 4) ^ ((rlB & 7) << 4))) = (rB < M) ? oB : 0u;
  }
  __syncthreads();

  int wr = wave & 1, wc = wave >> 1;
  int lrow = lane & 15, hi = lane >> 4;
  int lk = hi * 8;
  int rl = wr * 16 + lrow;

  f16x8 af[4];
#pragma unroll
  for (int ks = 0; ks < 4; ++ks)
    af[ks] = *(const f16x8*)(sTb + rl * 256 + ((ks * 64 + hi * 16) ^ ((rl & 7) << 4)));
  f32x4 acc[2];
#pragma unroll
  for (int n = 0; n < 2; ++n) acc[n] = (f32x4){0.f, 0.f, 0.f, 0.f};
#pragma unroll
  for (int ks = 0; ks < 4; ++ks) {
    f16x8 bf[2];
#pragma unroll
    for (int n = 0; n < 2; ++n)
      bf[n] = *(const f16x8*)(WT1 + (size_t)(wc * 32 + n * 16 + lrow) * 128 + ks * 32 + lk);
#pragma unroll
    for (int n = 0; n < 2; ++n)
      acc[n] = __builtin_amdgcn_mfma_f32_16x16x32_f16(af[ks], bf[n], acc[n], 0, 0, 0);
  }
  __syncthreads();

#pragma unroll
  for (int n = 0; n < 2; ++n) {
    int col = wc * 32 + n * 16 + lrow;
    float bia = b1[col];
#pragma unroll
    for (int r = 0; r < 4; ++r) {
      int rlw = wr * 16 + hi * 4 + r;
      float v = fmaxf(acc[n][r] + bia, 0.f);
      *(unsigned short*)(sTb + rlw * 256 + ((col * 2) ^ ((rlw & 7) << 4))) = f2h(v);
    }
  }
  __syncthreads();

#pragma unroll
  for (int ks = 0; ks < 4; ++ks)
    af[ks] = *(const f16x8*)(sTb + rl * 256 + ((ks * 64 + hi * 16) ^ ((rl & 7) << 4)));
#pragma unroll
  for (int n = 0; n < 2; ++n) acc[n] = (f32x4){0.f, 0.f, 0.f, 0.f};
#pragma unroll
  for (int ks = 0; ks < 4; ++ks) {
    f16x8 bf[2];
#pragma unroll
    for (int n = 0; n < 2; ++n)
      bf[n] = *(const f16x8*)(WT2 + (size_t)(wc * 32 + n * 16 + lrow) * 128 + ks * 32 + lk);
#pragma unroll
    for (int n = 0; n < 2; ++n)
      acc[n] = __builtin_amdgcn_mfma_f32_16x16x32_f16(af[ks], bf[n], acc[n], 0, 0, 0);
  }

  int rbase = row0 + wr * 16 + hi * 4;
#pragma unroll
  for (int n = 0; n < 2; ++n) {
    int col = wc * 32 + n * 16 + lrow;
    float bia = b2[col];
    float cs = 0.f, cq = 0.f;
#pragma unroll
    for (int r = 0; r < 4; ++r) {
      int rr = rbase + r;
      float v = fmaxf(acc[n][r] + bia, 0.f);
      if (rr < M) {
        Hout[(size_t)rr * 128 + col] = f2h(v);
        cs += v;
        cq += v * v;
      }
    }
    cs += __shfl_xor(cs, 16); cs += __shfl_xor(cs, 32);
    cq += __shfl_xor(cq, 16); cq += __shfl_xor(cq, 32);
    if (hi == 0) {
      atomicAdd(&s_sum[col], cs);
      atomicAdd(&s_sq[col], cq);
    }
  }
  __syncthreads();
  if (t < 128) {
    float* p = pstat + (size_t)blockIdx.x * 256;
    p[t] = s_sum[t];
    p[t + 128] = s_sq[t];
  }
}

__global__ __launch_bounds__(256) void bn_stats_kernel(const float* __restrict__ pstat, int nb,
                                                       const float* __restrict__ gamma,
                                                       const float* __restrict__ beta,
                                                       float* __restrict__ scale,
                                                       float* __restrict__ shift, float invM) {
  int c = blockIdx.x;
  int t = threadIdx.x;
  float s = 0.f, q = 0.f;
  for (int b = t; b < nb; b += 256) {
    const float* p = pstat + (size_t)b * 256;
    s += p[c];
    q += p[c + 128];
  }
#pragma unroll
  for (int off = 1; off < 64; off <<= 1) {
    s += __shfl_xor(s, off);
    q += __shfl_xor(q, off);
  }
  __shared__ float rs[4], rq[4];
  if ((t & 63) == 0) { rs[t >> 6] = s; rq[t >> 6] = q; }
  __syncthreads();
  if (t == 0) {
    float S = rs[0] + rs[1] + rs[2] + rs[3];
    float Q = rq[0] + rq[1] + rq[2] + rq[3];
    float mean = S * invM;
    float var = fmaxf(Q * invM - mean * mean, 0.f);
    float sc = gamma[c] * rsqrtf(var + 1e-5f);
    scale[c] = sc;
    shift[c] = beta[c] - mean * sc;
  }
}

__global__ __launch_bounds__(256) void pool_proj_kernel(const unsigned int* __restrict__ H,
                                                        const int* __restrict__ batch,
                                                        const float* __restrict__ scale,
                                                        const float* __restrict__ shift,
                                                        const float* __restrict__ Wp,
                                                        const float* __restrict__ bp,
                                                        float* __restrict__ out, int M) {
  int gid = blockIdx.x;
  int lo = 0, hi = M;
  while (lo < hi) { int mid = (lo + hi) >> 1; if (batch[mid] < gid) lo = mid + 1; else hi = mid; }
  int s = lo;
  lo = 0; hi = M;
  while (lo < hi) { int mid = (lo + hi) >> 1; if (batch[mid] < gid + 1) lo = mid + 1; else hi = mid; }
  int e = lo;
  int t = threadIdx.x;
  int cp = t & 63, rs_ = t >> 6;
  float ax = 0.f, ay = 0.f;
  for (int r = s + rs_; r < e; r += 4) {
    unsigned int v = H[(size_t)r * 64 + cp];
    ax += lo16(v);
    ay += hi16(v);
  }
  __shared__ float redx[256], redy[256];
  __shared__ float g[128];
  redx[t] = ax;
  redy[t] = ay;
  __syncthreads();
  if (t < 128) {
    int cpp = t >> 1;
    float sum;
    if (t & 1)
      sum = redy[cpp] + redy[64 + cpp] + redy[128 + cpp] + redy[192 + cpp];
    else
      sum = redx[cpp] + redx[64 + cpp] + redx[128 + cpp] + redx[192 + cpp];
    g[t] = sum * scale[t] + (float)(e - s) * shift[t];
  }
  __syncthreads();
  if (t < 128) {
    float a2 = bp[t];
#pragma unroll 8
    for (int k = 0; k < 128; ++k) a2 = fmaf(g[k], Wp[k * 128 + t], a2);
    out[gid * 128 + t] = fmaxf(a2, 0.f);
  }
}

extern "C" void kernel_launch(void* const* d_in, const int* in_sizes, int n_in,
                              void* d_out, int out_size, void* d_ws, size_t ws_size,
                              hipStream_t stream) {
  const float* x = (const float*)d_in[0];
  const int* ei = (const int*)d_in[1];
  const int* batch = (const int*)d_in[2];
  const float* W1 = (const float*)d_in[3];
  const float* b1 = (const float*)d_in[4];
  const float* W2 = (const float*)d_in[5];
  const float* b2 = (const float*)d_in[6];
  const float* gamma = (const float*)d_in[7];
  const float* beta = (const float*)d_in[8];
  const float* Wp = (const float*)d_in[9];
  const float* bp = (const float*)d_in[10];
  float* out = (float*)d_out;

  int M = in_sizes[0] / 128;
  int E = in_sizes[1] / 2;
  int L = in_sizes[3] / (128 * 128);
  int G = out_size / 128;
  const int* srcp = ei;
  const int* dstp = ei + E;

  char* w = (char*)d_ws;
  auto alloc = [&](size_t bytes) {
    char* p = w;
    w += (bytes + 255) & ~(size_t)255;
    return p;
  };
  int nblk = (M + 31) / 32;
  int CB = (M + 511) >> 9;
  unsigned int* bufA = (unsigned int*)alloc((size_t)M * 64 * 4);
  unsigned int* bufB = (unsigned int*)alloc((size_t)M * 64 * 4);
  unsigned int* aggbuf = (unsigned int*)alloc((size_t)M * 64 * 4);
  unsigned short* WT = (unsigned short*)alloc((size_t)L * 2 * 16384 * 2);
  int* partial = (int*)alloc((size_t)HB * 128 * 4);
  int* ccursor = (int*)alloc(128 * 4);
  int* cbase = (int*)alloc(132 * 4);
  int* offsets = (int*)alloc((size_t)(M + 1) * 4);
  unsigned int* tmp = (unsigned int*)alloc((size_t)E * 4);
  unsigned short* srcs = (unsigned short*)alloc((size_t)E * 2);
  float* pstat = (float*)alloc((size_t)nblk * 256 * 4);
  float* stats = (float*)alloc(2 * 128 * 4);
  float* scale = stats;
  float* shift = stats + 128;

  prep_fused_kernel<<<2048, 256, 0, stream>>>(x, bufA, W1, W2, WT, dstp, partial, scale, shift,
                                              M, E, L);
  cscan_kernel<<<1, 128, 0, stream>>>(partial, ccursor, cbase, E);
  sortA_kernel<<<(E + EPB - 1) / EPB, 256, 0, stream>>>(srcp, dstp, ccursor, tmp, E);
  sortB_kernel<<<CB, 512, 0, stream>>>(tmp, cbase, offsets, srcs, M, E);

  float invM = 1.0f / (float)M;
  unsigned int* cur = bufA;
  unsigned int* nxt = bufB;
  for (int l = 0; l < L; ++l) {
    if ((l & 1) == 0) {
      // NEW split path: XCD-pinned slice aggregation + MLP
      agg_kernel<<<nblk * 8, 256, 0, stream>>>(cur, offsets, srcs, scale, shift, aggbuf, M);
      mlp_kernel<<<nblk, 512, 0, stream>>>(aggbuf, WT + (size_t)(2 * l) * 16384, b1 + l * 128,
                                           WT + (size_t)(2 * l + 1) * 16384, b2 + l * 128,
                                           (unsigned short*)nxt, pstat, M);
    } else {
      // control: round-13 fused layer
      layer_kernel<<<nblk, 512, 0, stream>>>(
          cur, offsets, srcs, scale, shift, WT + (size_t)(2 * l) * 16384, b1 + l * 128,
          WT + (size_t)(2 * l + 1) * 16384, b2 + l * 128, (unsigned short*)nxt, pstat, M);
    }
    bn_stats_kernel<<<128, 256, 0, stream>>>(pstat, nblk, gamma + l * 128, beta + l * 128,
                                             scale, shift, invM);
    unsigned int* tmpp = cur; cur = nxt; nxt = tmpp;
  }

  pool_proj_kernel<<<G, 256, 0, stream>>>(cur, batch, scale, shift, Wp, bp, out, M);
}

// Round 15
// 356.671 us; speedup vs baseline: 1.6154x; 1.6154x over previous
//
#include <hip/hip_runtime.h>

// ---------------------------------------------------------------------------
// GIN encoder, fp16 feature path + MFMA, fused per-layer kernel (512 thr).
// ROUND-15 = exact revert to round-13 (best: 356.5 us). Round-14's XCD-pinned
// column-slice gather REGRESSED (agg 141 us, FETCH 184 MB): 32B slice reads
// still pull >=64B lines shared across slices -> fetch amplification, no
// cross-XCD reuse. Locality question closed: the random row gather is pinned
// at the compulsory ~79 MB/layer fetched at the ~1.15 TB/s random-line fill
// rate (rounds 6-14: issue rate, latency depth, L1 policy, phasing, sorting,
// quartering, slicing - all null or negative).
// Structure: prep_fused (x->fp16 + W->WT + affine + coarse hist) -> cscan ->
// sortA (coarse bucket sort) -> sortB (per-bucket LDS counting sort ->
// offsets+srcs) -> 4x [layer_kernel -> bn_stats] -> pool_proj.
// ---------------------------------------------------------------------------

typedef __attribute__((ext_vector_type(8))) _Float16 f16x8;
typedef __attribute__((ext_vector_type(4))) float f32x4;

static __device__ __forceinline__ float h2f(unsigned short u) {
  return (float)__builtin_bit_cast(_Float16, u);
}
static __device__ __forceinline__ unsigned short f2h(float f) {
  return __builtin_bit_cast(unsigned short, (_Float16)f);
}
static __device__ __forceinline__ float lo16(unsigned int v) { return h2f((unsigned short)(v & 0xffffu)); }
static __device__ __forceinline__ float hi16(unsigned int v) { return h2f((unsigned short)(v >> 16)); }

#define HB 392  // blocks participating in the coarse histogram

// ---- fused prep: x->fp16, W->WT, affine init, coarse dst-hist partials ----
__global__ __launch_bounds__(256) void prep_fused_kernel(
    const float* __restrict__ x, unsigned int* __restrict__ h,
    const float* __restrict__ W1, const float* __restrict__ W2,
    unsigned short* __restrict__ WT, const int* __restrict__ dst,
    int* __restrict__ partial, float* __restrict__ scale, float* __restrict__ shift,
    int M, int E, int Ltot) {
  __shared__ int hcnt[128];
  int t = threadIdx.x;
  int tid = blockIdx.x * 256 + t;
  int stride = gridDim.x * 256;
  bool doHist = (blockIdx.x < HB);
  if (doHist) {
    if (t < 128) hcnt[t] = 0;
    __syncthreads();
    for (int e = blockIdx.x * 256 + t; e < E; e += HB * 256)
      atomicAdd(&hcnt[dst[e] >> 9], 1);
  }
  // x -> fp16 packed
  const float2* x2 = (const float2*)x;
  int total = M * 64;
  for (int i = tid; i < total; i += stride) {
    float2 v = x2[i];
    h[i] = (unsigned int)f2h(v.x) | ((unsigned int)f2h(v.y) << 16);
  }
  // W -> WT (transposed fp16): WT[m][n][k] = f16(W_m[k][n])
  int wtotal = Ltot * 2 * 16384;
  for (int idx = tid; idx < wtotal; idx += stride) {
    int m = idx >> 14;
    int rem = idx & 16383;
    int n = rem >> 7, k = rem & 127;
    const float* W = ((m & 1) == 0) ? (W1 + (size_t)(m >> 1) * 16384)
                                    : (W2 + (size_t)(m >> 1) * 16384);
    WT[idx] = f2h(W[k * 128 + n]);
  }
  if (tid < 128) { scale[tid] = 1.f; shift[tid] = 0.f; }
  if (doHist) {
    __syncthreads();
    if (t < 128) partial[blockIdx.x * 128 + t] = hcnt[t];
  }
}

// ---- sum partials + exclusive scan of 128 coarse buckets ----
__global__ __launch_bounds__(128) void cscan_kernel(const int* __restrict__ partial,
                                                    int* __restrict__ ccursor,
                                                    int* __restrict__ cbase, int E) {
  __shared__ int buf[2][128];
  int t = threadIdx.x;
  int s = 0;
  for (int k = 0; k < HB; ++k) s += partial[k * 128 + t];
  buf[0][t] = s;
  __syncthreads();
  int cur = 0;
  for (int off = 1; off < 128; off <<= 1) {
    buf[cur ^ 1][t] = buf[cur][t] + ((t >= off) ? buf[cur][t - off] : 0);
    __syncthreads();
    cur ^= 1;
  }
  int excl = buf[cur][t] - s;
  ccursor[t] = excl;
  cbase[t] = excl;
  if (t == 127) cbase[128] = E;
}

// ---- passA: coarse sort edges into 512-row buckets; packed v=(d<<16)|s ----
#define EPB 4096
__global__ __launch_bounds__(256) void sortA_kernel(const int* __restrict__ src,
                                                    const int* __restrict__ dst,
                                                    int* __restrict__ ccursor,
                                                    unsigned int* __restrict__ tmp, int E) {
  __shared__ int cnt[128], pref[128], gbase[128];
  __shared__ int scanbuf[2][128];
  __shared__ unsigned int vals[EPB];
  int t = threadIdx.x;
  int base = blockIdx.x * EPB;
  int nloc = min(EPB, E - base);
  if (t < 128) cnt[t] = 0;
  __syncthreads();

  unsigned int vj[16];
  int rj[16];
#pragma unroll
  for (int j = 0; j < 16; ++j) {
    int e = base + j * 256 + t;
    vj[j] = 0u;
    rj[j] = -1;
    if (e < base + nloc) {
      int s = src[e], d = dst[e];
      unsigned int v = ((unsigned int)d << 16) | (unsigned int)s;
      vj[j] = v;
      rj[j] = atomicAdd(&cnt[v >> 25], 1);
    }
  }
  __syncthreads();
  if (t < 128) scanbuf[0][t] = cnt[t];
  __syncthreads();
  int cur = 0;
  for (int off = 1; off < 128; off <<= 1) {
    if (t < 128) scanbuf[cur ^ 1][t] = scanbuf[cur][t] + ((t >= off) ? scanbuf[cur][t - off] : 0);
    __syncthreads();
    cur ^= 1;
  }
  if (t < 128) pref[t] = scanbuf[cur][t] - cnt[t];
  __syncthreads();
  if (t < 128 && cnt[t] > 0) gbase[t] = atomicAdd(&ccursor[t], cnt[t]);
  __syncthreads();
#pragma unroll
  for (int j = 0; j < 16; ++j) {
    if (rj[j] >= 0) vals[pref[vj[j] >> 25] + rj[j]] = vj[j];
  }
  __syncthreads();
  for (int j = t; j < nloc; j += 256) {
    unsigned int v = vals[j];
    int b = v >> 25;
    tmp[gbase[b] + (j - pref[b])] = v;
  }
}

// ---- passB: per-bucket LDS counting sort -> offsets[] + srcs[] ----
__global__ __launch_bounds__(512) void sortB_kernel(const unsigned int* __restrict__ tmp,
                                                    const int* __restrict__ cbase,
                                                    int* __restrict__ offsets,
                                                    unsigned short* __restrict__ srcs,
                                                    int M, int E) {
  __shared__ int lcnt[512];
  __shared__ int sbuf[2][512];
  int b = blockIdx.x;
  int t = threadIdx.x;
  int e0 = cbase[b], e1 = cbase[b + 1];
  int r0 = b << 9;
  lcnt[t] = 0;
  __syncthreads();
  for (int e = e0 + t; e < e1; e += 512) atomicAdd(&lcnt[(tmp[e] >> 16) & 511], 1);
  __syncthreads();
  sbuf[0][t] = lcnt[t];
  __syncthreads();
  int cur = 0;
  for (int off = 1; off < 512; off <<= 1) {
    sbuf[cur ^ 1][t] = sbuf[cur][t] + ((t >= off) ? sbuf[cur][t - off] : 0);
    __syncthreads();
    cur ^= 1;
  }
  int excl = sbuf[cur][t] - lcnt[t];
  int r = r0 + t;
  if (r < M) offsets[r] = e0 + excl;
  if (r == M - 1) offsets[M] = E;
  __syncthreads();
  lcnt[t] = e0 + excl;  // running global cursor per row
  __syncthreads();
  for (int e = e0 + t; e < e1; e += 512) {
    unsigned int v = tmp[e];
    int p = atomicAdd(&lcnt[(v >> 16) & 511], 1);
    srcs[p] = (unsigned short)(v & 0xffffu);
  }
}

// ---- fused layer: gather+BN -> LDS -> GEMM1 -> LDS -> GEMM2 -> Hout+stats ----
// 32-row tile, 8 waves; each wave gathers 4 rows (2 in flight, unroll-4).
// LDS tile swizzle: fp16 col c of row rl at byte (rl*256 + ((c*2) ^ ((rl&7)<<4))).
// MFMA frag layouts (m89-verified, rounds 3-13).
__global__ __launch_bounds__(512, 8) void layer_kernel(
    const unsigned int* __restrict__ Hin,  // M x 64 uints (fp16x2, row-major)
    const int* __restrict__ offsets,       // M + 1
    const unsigned short* __restrict__ srcs,
    const float* __restrict__ scale, const float* __restrict__ shift,
    const unsigned short* __restrict__ WT1, const float* __restrict__ b1,
    const unsigned short* __restrict__ WT2, const float* __restrict__ b2,
    unsigned short* __restrict__ Hout,  // M x 128 fp16 row-major
    float* __restrict__ pstat, int M) {
  __shared__ unsigned short sT[32 * 128];
  __shared__ float s_sum[128], s_sq[128];
  int t = threadIdx.x;
  if (t < 128) { s_sum[t] = 0.f; s_sq[t] = 0.f; }
  int wave = t >> 6, lane = t & 63;
  int row0 = blockIdx.x * 32;
  char* sTb = (char*)sT;
  float sc0 = scale[2 * lane], sc1 = scale[2 * lane + 1];
  float sh0 = shift[2 * lane], sh1 = shift[2 * lane + 1];

  for (int i = 0; i < 4; i += 2) {
    int rA = row0 + wave * 4 + i;
    int rB = rA + 1;
    float axA = 0.f, ayA = 0.f, axB = 0.f, ayB = 0.f;
    int eA = 0, eA1 = 0, eB = 0, eB1 = 0;
    if (rA < M) {
      eA = offsets[rA]; eA1 = offsets[rA + 1];
      unsigned int s = Hin[(size_t)rA * 64 + lane];
      axA = lo16(s); ayA = hi16(s);
    }
    if (rB < M) {
      eB = offsets[rB]; eB1 = offsets[rB + 1];
      unsigned int s = Hin[(size_t)rB * 64 + lane];
      axB = lo16(s); ayB = hi16(s);
    }
    int dA = eA1 - eA, dB = eB1 - eB;
    while (eA + 4 <= eA1 && eB + 4 <= eB1) {
      int a0 = srcs[eA], a1 = srcs[eA + 1], a2 = srcs[eA + 2], a3 = srcs[eA + 3];
      int c0 = srcs[eB], c1 = srcs[eB + 1], c2 = srcs[eB + 2], c3 = srcs[eB + 3];
      unsigned int vA0 = Hin[(size_t)a0 * 64 + lane];
      unsigned int vA1 = Hin[(size_t)a1 * 64 + lane];
      unsigned int vA2 = Hin[(size_t)a2 * 64 + lane];
      unsigned int vA3 = Hin[(size_t)a3 * 64 + lane];
      unsigned int vB0 = Hin[(size_t)c0 * 64 + lane];
      unsigned int vB1 = Hin[(size_t)c1 * 64 + lane];
      unsigned int vB2 = Hin[(size_t)c2 * 64 + lane];
      unsigned int vB3 = Hin[(size_t)c3 * 64 + lane];
      axA += lo16(vA0) + lo16(vA1) + lo16(vA2) + lo16(vA3);
      ayA += hi16(vA0) + hi16(vA1) + hi16(vA2) + hi16(vA3);
      axB += lo16(vB0) + lo16(vB1) + lo16(vB2) + lo16(vB3);
      ayB += hi16(vB0) + hi16(vB1) + hi16(vB2) + hi16(vB3);
      eA += 4; eB += 4;
    }
    while (eA + 4 <= eA1) {
      int a0 = srcs[eA], a1 = srcs[eA + 1], a2 = srcs[eA + 2], a3 = srcs[eA + 3];
      unsigned int v0 = Hin[(size_t)a0 * 64 + lane];
      unsigned int v1 = Hin[(size_t)a1 * 64 + lane];
      unsigned int v2 = Hin[(size_t)a2 * 64 + lane];
      unsigned int v3 = Hin[(size_t)a3 * 64 + lane];
      axA += lo16(v0) + lo16(v1) + lo16(v2) + lo16(v3);
      ayA += hi16(v0) + hi16(v1) + hi16(v2) + hi16(v3);
      eA += 4;
    }
    while (eB + 4 <= eB1) {
      int c0 = srcs[eB], c1 = srcs[eB + 1], c2 = srcs[eB + 2], c3 = srcs[eB + 3];
      unsigned int v0 = Hin[(size_t)c0 * 64 + lane];
      unsigned int v1 = Hin[(size_t)c1 * 64 + lane];
      unsigned int v2 = Hin[(size_t)c2 * 64 + lane];
      unsigned int v3 = Hin[(size_t)c3 * 64 + lane];
      axB += lo16(v0) + lo16(v1) + lo16(v2) + lo16(v3);
      ayB += hi16(v0) + hi16(v1) + hi16(v2) + hi16(v3);
      eB += 4;
    }
    for (; eA < eA1; ++eA) {
      unsigned int v = Hin[(size_t)srcs[eA] * 64 + lane];
      axA += lo16(v); ayA += hi16(v);
    }
    for (; eB < eB1; ++eB) {
      unsigned int v = Hin[(size_t)srcs[eB] * 64 + lane];
      axB += lo16(v); ayB += hi16(v);
    }
    int rlA = wave * 4 + i, rlB = rlA + 1;
    float dA1 = (float)(dA + 1), dB1 = (float)(dB + 1);
    unsigned int oA = (unsigned int)f2h(axA * sc0 + dA1 * sh0) |
                      ((unsigned int)f2h(ayA * sc1 + dA1 * sh1) << 16);
    unsigned int oB = (unsigned int)f2h(axB * sc0 + dB1 * sh0) |
                      ((unsigned int)f2h(ayB * sc1 + dB1 * sh1) << 16);
    *(unsigned int*)(sTb + rlA * 256 + ((lane * 4) ^ ((rlA & 7) << 4))) = (rA < M) ? oA : 0u;
    *(unsigned int*)(sTb + rlB * 256 + ((lane * 4) ^ ((rlB & 7) << 4))) = (rB < M) ? oB : 0u;
  }
  __syncthreads();

  int wr = wave & 1, wc = wave >> 1;
  int lrow = lane & 15, hi = lane >> 4;
  int lk = hi * 8;
  int rl = wr * 16 + lrow;

  // GEMM1
  f16x8 af[4];
#pragma unroll
  for (int ks = 0; ks < 4; ++ks)
    af[ks] = *(const f16x8*)(sTb + rl * 256 + ((ks * 64 + hi * 16) ^ ((rl & 7) << 4)));
  f32x4 acc[2];
#pragma unroll
  for (int n = 0; n < 2; ++n) acc[n] = (f32x4){0.f, 0.f, 0.f, 0.f};
#pragma unroll
  for (int ks = 0; ks < 4; ++ks) {
    f16x8 bf[2];
#pragma unroll
    for (int n = 0; n < 2; ++n)
      bf[n] = *(const f16x8*)(WT1 + (size_t)(wc * 32 + n * 16 + lrow) * 128 + ks * 32 + lk);
#pragma unroll
    for (int n = 0; n < 2; ++n)
      acc[n] = __builtin_amdgcn_mfma_f32_16x16x32_f16(af[ks], bf[n], acc[n], 0, 0, 0);
  }
  __syncthreads();

#pragma unroll
  for (int n = 0; n < 2; ++n) {
    int col = wc * 32 + n * 16 + lrow;
    float bia = b1[col];
#pragma unroll
    for (int r = 0; r < 4; ++r) {
      int rlw = wr * 16 + hi * 4 + r;
      float v = fmaxf(acc[n][r] + bia, 0.f);
      *(unsigned short*)(sTb + rlw * 256 + ((col * 2) ^ ((rlw & 7) << 4))) = f2h(v);
    }
  }
  __syncthreads();

  // GEMM2
#pragma unroll
  for (int ks = 0; ks < 4; ++ks)
    af[ks] = *(const f16x8*)(sTb + rl * 256 + ((ks * 64 + hi * 16) ^ ((rl & 7) << 4)));
#pragma unroll
  for (int n = 0; n < 2; ++n) acc[n] = (f32x4){0.f, 0.f, 0.f, 0.f};
#pragma unroll
  for (int ks = 0; ks < 4; ++ks) {
    f16x8 bf[2];
#pragma unroll
    for (int n = 0; n < 2; ++n)
      bf[n] = *(const f16x8*)(WT2 + (size_t)(wc * 32 + n * 16 + lrow) * 128 + ks * 32 + lk);
#pragma unroll
    for (int n = 0; n < 2; ++n)
      acc[n] = __builtin_amdgcn_mfma_f32_16x16x32_f16(af[ks], bf[n], acc[n], 0, 0, 0);
  }

  int rbase = row0 + wr * 16 + hi * 4;
#pragma unroll
  for (int n = 0; n < 2; ++n) {
    int col = wc * 32 + n * 16 + lrow;
    float bia = b2[col];
    float cs = 0.f, cq = 0.f;
#pragma unroll
    for (int r = 0; r < 4; ++r) {
      int rr = rbase + r;
      float v = fmaxf(acc[n][r] + bia, 0.f);
      if (rr < M) {
        Hout[(size_t)rr * 128 + col] = f2h(v);
        cs += v;
        cq += v * v;
      }
    }
    cs += __shfl_xor(cs, 16); cs += __shfl_xor(cs, 32);
    cq += __shfl_xor(cq, 16); cq += __shfl_xor(cq, 32);
    if (hi == 0) {
      atomicAdd(&s_sum[col], cs);
      atomicAdd(&s_sq[col], cq);
    }
  }
  __syncthreads();
  if (t < 128) {
    float* p = pstat + (size_t)blockIdx.x * 256;
    p[t] = s_sum[t];
    p[t + 128] = s_sq[t];
  }
}

// reduce per-block partials -> scale/shift for the next layer
__global__ __launch_bounds__(256) void bn_stats_kernel(const float* __restrict__ pstat, int nb,
                                                       const float* __restrict__ gamma,
                                                       const float* __restrict__ beta,
                                                       float* __restrict__ scale,
                                                       float* __restrict__ shift, float invM) {
  int c = blockIdx.x;
  int t = threadIdx.x;
  float s = 0.f, q = 0.f;
  for (int b = t; b < nb; b += 256) {
    const float* p = pstat + (size_t)b * 256;
    s += p[c];
    q += p[c + 128];
  }
#pragma unroll
  for (int off = 1; off < 64; off <<= 1) {
    s += __shfl_xor(s, off);
    q += __shfl_xor(q, off);
  }
  __shared__ float rs[4], rq[4];
  if ((t & 63) == 0) { rs[t >> 6] = s; rq[t >> 6] = q; }
  __syncthreads();
  if (t == 0) {
    float S = rs[0] + rs[1] + rs[2] + rs[3];
    float Q = rq[0] + rq[1] + rq[2] + rq[3];
    float mean = S * invM;
    float var = fmaxf(Q * invM - mean * mean, 0.f);
    float sc = gamma[c] * rsqrtf(var + 1e-5f);
    scale[c] = sc;
    shift[c] = beta[c] - mean * sc;
  }
}

// ---- fused pool (last layer BN) + projection ----
__global__ __launch_bounds__(256) void pool_proj_kernel(const unsigned int* __restrict__ H,
                                                        const int* __restrict__ batch,
                                                        const float* __restrict__ scale,
                                                        const float* __restrict__ shift,
                                                        const float* __restrict__ Wp,
                                                        const float* __restrict__ bp,
                                                        float* __restrict__ out, int M) {
  int gid = blockIdx.x;
  int lo = 0, hi = M;
  while (lo < hi) { int mid = (lo + hi) >> 1; if (batch[mid] < gid) lo = mid + 1; else hi = mid; }
  int s = lo;
  lo = 0; hi = M;
  while (lo < hi) { int mid = (lo + hi) >> 1; if (batch[mid] < gid + 1) lo = mid + 1; else hi = mid; }
  int e = lo;
  int t = threadIdx.x;
  int cp = t & 63, rs_ = t >> 6;
  float ax = 0.f, ay = 0.f;
  for (int r = s + rs_; r < e; r += 4) {
    unsigned int v = H[(size_t)r * 64 + cp];
    ax += lo16(v);
    ay += hi16(v);
  }
  __shared__ float redx[256], redy[256];
  __shared__ float g[128];
  redx[t] = ax;
  redy[t] = ay;
  __syncthreads();
  if (t < 128) {
    int cpp = t >> 1;
    float sum;
    if (t & 1)
      sum = redy[cpp] + redy[64 + cpp] + redy[128 + cpp] + redy[192 + cpp];
    else
      sum = redx[cpp] + redx[64 + cpp] + redx[128 + cpp] + redx[192 + cpp];
    g[t] = sum * scale[t] + (float)(e - s) * shift[t];
  }
  __syncthreads();
  if (t < 128) {
    float a2 = bp[t];
#pragma unroll 8
    for (int k = 0; k < 128; ++k) a2 = fmaf(g[k], Wp[k * 128 + t], a2);
    out[gid * 128 + t] = fmaxf(a2, 0.f);
  }
}

extern "C" void kernel_launch(void* const* d_in, const int* in_sizes, int n_in,
                              void* d_out, int out_size, void* d_ws, size_t ws_size,
                              hipStream_t stream) {
  const float* x = (const float*)d_in[0];
  const int* ei = (const int*)d_in[1];
  const int* batch = (const int*)d_in[2];
  const float* W1 = (const float*)d_in[3];
  const float* b1 = (const float*)d_in[4];
  const float* W2 = (const float*)d_in[5];
  const float* b2 = (const float*)d_in[6];
  const float* gamma = (const float*)d_in[7];
  const float* beta = (const float*)d_in[8];
  const float* Wp = (const float*)d_in[9];
  const float* bp = (const float*)d_in[10];
  float* out = (float*)d_out;

  int M = in_sizes[0] / 128;
  int E = in_sizes[1] / 2;
  int L = in_sizes[3] / (128 * 128);
  int G = out_size / 128;
  const int* srcp = ei;
  const int* dstp = ei + E;

  char* w = (char*)d_ws;
  auto alloc = [&](size_t bytes) {
    char* p = w;
    w += (bytes + 255) & ~(size_t)255;
    return p;
  };
  int nblk = (M + 31) / 32;
  int CB = (M + 511) >> 9;  // coarse buckets (512 rows each), <=128
  unsigned int* bufA = (unsigned int*)alloc((size_t)M * 64 * 4);
  unsigned int* bufB = (unsigned int*)alloc((size_t)M * 64 * 4);
  unsigned short* WT = (unsigned short*)alloc((size_t)L * 2 * 16384 * 2);
  int* partial = (int*)alloc((size_t)HB * 128 * 4);
  int* ccursor = (int*)alloc(128 * 4);
  int* cbase = (int*)alloc(132 * 4);
  int* offsets = (int*)alloc((size_t)(M + 1) * 4);
  unsigned int* tmp = (unsigned int*)alloc((size_t)E * 4);
  unsigned short* srcs = (unsigned short*)alloc((size_t)E * 2);
  float* pstat = (float*)alloc((size_t)nblk * 256 * 4);
  float* stats = (float*)alloc(2 * 128 * 4);
  float* scale = stats;
  float* shift = stats + 128;

  prep_fused_kernel<<<2048, 256, 0, stream>>>(x, bufA, W1, W2, WT, dstp, partial, scale, shift,
                                              M, E, L);
  cscan_kernel<<<1, 128, 0, stream>>>(partial, ccursor, cbase, E);
  sortA_kernel<<<(E + EPB - 1) / EPB, 256, 0, stream>>>(srcp, dstp, ccursor, tmp, E);
  sortB_kernel<<<CB, 512, 0, stream>>>(tmp, cbase, offsets, srcs, M, E);

  float invM = 1.0f / (float)M;
  unsigned int* cur = bufA;
  unsigned int* nxt = bufB;
  for (int l = 0; l < L; ++l) {
    layer_kernel<<<nblk, 512, 0, stream>>>(
        cur, offsets, srcs, scale, shift, WT + (size_t)(2 * l) * 16384, b1 + l * 128,
        WT + (size_t)(2 * l + 1) * 16384, b2 + l * 128, (unsigned short*)nxt, pstat, M);
    bn_stats_kernel<<<128, 256, 0, stream>>>(pstat, nblk, gamma + l * 128, beta + l * 128,
                                             scale, shift, invM);
    unsigned int* tmpp = cur; cur = nxt; nxt = tmpp;
  }

  pool_proj_kernel<<<G, 256, 0, stream>>>(cur, batch, scale, shift, Wp, bp, out, M);
}